// Round 5
// baseline (1038.516 us; speedup 1.0000x reference)
//
#include <hip/hip_runtime.h>
#include <float.h>
#include <math.h>

#define B_ 2
#define C_ 64
#define H_ 64
#define W_ 64
#define M1 62
#define NP (M1*M1)      // 3844
#define WIN 30
#define KK 5
#define NSEL 16
#define HS 128

#define OUT_SCORE_SZ (B_*KK*HS*HS)       // 163840
#define OUT_IDX_OFF  (OUT_SCORE_SZ)
#define OUT_IDX_SZ   (B_*NP*KK)          // 38440
#define OUT_DIFF_OFF (OUT_IDX_OFF+OUT_IDX_SZ)
#define OUT_DIFF_SZ  (B_*KK*C_*HS*HS)    // 10485760

// ws layout in floats
#define WS_XNORM 0
#define WS_SV    8192                     // B_*KK*NP = 38440 (padded region 40960)
#define WS_DSUM  (8192+40960)             // B_*KK*C_*NP = 2460160

__global__ __launch_bounds__(256) void xnorm_kernel(const float* __restrict__ xe,
                                                    float* __restrict__ xn) {
    int idx = blockIdx.x * 256 + threadIdx.x;
    if (idx >= B_ * NP) return;
    int b = idx / NP, m = idx % NP;
    int r = m / M1, s = m % M1;
    float acc = 0.f;
    for (int c = 0; c < C_; c++) {
        #pragma unroll
        for (int p = 0; p < 9; p++) {
            float v = xe[((b * C_ + c) * H_ + r + p / 3) * W_ + s + p % 3];
            acc += v * v;
        }
    }
    xn[idx] = acc;
}

// numpy pairwise_sum leaf (n=72, scalar 8-accumulator base case), element
// provider is a lambda-ish via macro: values v(e) for e in [base, base+72)
template <typename F>
__device__ __forceinline__ float pw72(F v, int base) {
    float r0 = v(base + 0), r1 = v(base + 1), r2 = v(base + 2), r3 = v(base + 3);
    float r4 = v(base + 4), r5 = v(base + 5), r6 = v(base + 6), r7 = v(base + 7);
    for (int i = 8; i < 72; i += 8) {
        r0 += v(base + i + 0); r1 += v(base + i + 1);
        r2 += v(base + i + 2); r3 += v(base + i + 3);
        r4 += v(base + i + 4); r5 += v(base + i + 5);
        r6 += v(base + i + 6); r7 += v(base + i + 7);
    }
    return ((r0 + r1) + (r2 + r3)) + ((r4 + r5) + (r6 + r7));
}

__global__ __launch_bounds__(256) void knn_kernel(const float* __restrict__ xe,
                                                  const float* __restrict__ ye,
                                                  const float* __restrict__ xn,
                                                  float* __restrict__ out_idx,
                                                  float* __restrict__ sv_ws,
                                                  float* __restrict__ dsum_ws) {
    __shared__ float ys[9 * 64];            // [p][c] layout for dot/dsum phases
    __shared__ float ysE[576];              // e-order (c*9+p) for np emulation
    __shared__ float xs[8 * 32 * 32 + 8];   // [ch][row][col], 8-ch chunk
    __shared__ float keyA[WIN * WIN];       // 900
    __shared__ float rk[256];
    __shared__ int   ri[256];
    __shared__ int   topW[NSEL];
    __shared__ float keyEmu[NSEL];
    __shared__ float selKey[KK];
    __shared__ int   selW[KK];

    const int q = blockIdx.x;
    const int b = q / NP, m = q % NP;
    const int r = m / M1, s = m % M1;
    const int si = min(max(r - 15, 0), M1 - WIN);  // clip to [0,32]
    const int sj = min(max(s - 15, 0), M1 - WIN);
    const int tid = threadIdx.x;

    // stage y patch in both layouts
    for (int t = tid; t < 576; t += 256) {
        int p = t >> 6, c = t & 63;
        float v = ye[((b * C_ + c) * H_ + r + p / 3) * W_ + s + p % 3];
        ys[p * 64 + c] = v;
        ysE[c * 9 + p] = v;
    }

    // bulk f32 dot prescreen: 240 active threads, thread = (wi, j8), 4 candidates
    const int wi = tid >> 3;
    const int j8 = tid & 7;
    const int wj0 = j8 * 4;
    const bool active = (tid < 240);
    float dacc[4] = {0.f, 0.f, 0.f, 0.f};

    for (int cc = 0; cc < C_; cc += 8) {
        __syncthreads();
        #pragma unroll
        for (int kk = 0; kk < 32; kk++) {
            int ch = kk >> 2, rr = kk & 3;
            int pix = rr * 256 + tid;
            int row = pix >> 5, col = pix & 31;
            xs[ch * 1024 + pix] = xe[((b * C_ + cc + ch) * H_ + si + row) * W_ + sj + col];
        }
        __syncthreads();
        if (active) {
            float yv[9][8];
            #pragma unroll
            for (int p = 0; p < 9; p++) {
                float4 a = *(const float4*)&ys[p * 64 + cc];
                float4 c4 = *(const float4*)&ys[p * 64 + cc + 4];
                yv[p][0] = a.x;  yv[p][1] = a.y;  yv[p][2] = a.z;  yv[p][3] = a.w;
                yv[p][4] = c4.x; yv[p][5] = c4.y; yv[p][6] = c4.z; yv[p][7] = c4.w;
            }
            #pragma unroll
            for (int ch = 0; ch < 8; ch++) {
                #pragma unroll
                for (int i = 0; i < 3; i++) {
                    const float* xp = &xs[ch * 1024 + (wi + i) * 32 + wj0];
                    float4 a = *(const float4*)xp;
                    float4 c4 = *(const float4*)(xp + 4);
                    float xf[8] = {a.x, a.y, a.z, a.w, c4.x, c4.y, c4.z, c4.w};
                    #pragma unroll
                    for (int o = 0; o < 4; o++) {
                        #pragma unroll
                        for (int jj = 0; jj < 3; jj++) {
                            dacc[o] += yv[i * 3 + jj][ch] * xf[o + jj];
                        }
                    }
                }
            }
        }
    }

    if (active) {
        #pragma unroll
        for (int o = 0; o < 4; o++) {
            int wj = wj0 + o;
            if (wj < WIN) {
                int n = (si + wi) * M1 + (sj + wj);
                keyA[wi * WIN + wj] = xn[b * NP + n] - 2.0f * dacc[o];
            }
        }
    }
    __syncthreads();

    // extract top-NSEL by prescreen key (tie -> smaller window index)
    for (int it = 0; it < NSEL; it++) {
        float bk = FLT_MAX;
        int bw = 1 << 30;
        for (int w = tid; w < WIN * WIN; w += 256) {
            float kv = keyA[w];
            if (kv < bk || (kv == bk && w < bw)) { bk = kv; bw = w; }
        }
        rk[tid] = bk; ri[tid] = bw;
        __syncthreads();
        for (int off = 128; off > 0; off >>= 1) {
            if (tid < off) {
                float k2 = rk[tid + off]; int w2 = ri[tid + off];
                if (k2 < rk[tid] || (k2 == rk[tid] && w2 < ri[tid])) { rk[tid] = k2; ri[tid] = w2; }
            }
            __syncthreads();
        }
        if (tid == 0) { topW[it] = ri[0]; keyA[ri[0]] = FLT_MAX; }
        __syncthreads();
    }

    // ---- bitwise np-f32 emulation of ref keys for the 16 survivors ----
    // 16 threads per candidate: cand = tid>>4, lane j = tid&15
    {
        const int cand = tid >> 4;
        const int j = tid & 15;
        const int w = topW[cand];
        const int px = si + w / WIN, py = sj + w % WIN;
        const float* xb = xe + (size_t)b * C_ * H_ * W_;

        // einsum E: npyv AVX512 single-vaccum nested-FMA; lane j owns e = j mod 16
        float acc = 0.f;
        for (int t = 0; t < 36; t++) {
            int e = t * 16 + j;
            int c = e / 9, p = e - c * 9;
            float xv = xb[(c * H_ + px + p / 3) * W_ + py + (p % 3)];
            acc = fmaf(ysE[e], xv, acc);
        }
        // npyv_sum halves tree 16->8->4->2->1 (butterfly == tree, f32 add commutes)
        float E = acc;
        E = E + __shfl_xor(E, 8, 16);
        E = E + __shfl_xor(E, 4, 16);
        E = E + __shfl_xor(E, 2, 16);
        E = E + __shfl_xor(E, 1, 16);

        // xnorm / ynorm: numpy pairwise_sum over 576 squares.
        // Leaves of 72 (scalar 8-acc base), tree: (L0+L1)+(L2+L3) etc.
        const int l = j & 7;  // leaf index; threads 8..15 duplicate
        auto xv2 = [&](int e) {
            int c = e / 9, p = e - c * 9;
            float v = xb[(c * H_ + px + p / 3) * W_ + py + (p % 3)];
            return v * v;
        };
        auto yv2 = [&](int e) { float v = ysE[e]; return v * v; };
        float xleaf = pw72(xv2, l * 72);
        float yleaf = pw72(yv2, l * 72);
        // tree over 8 leaves: xor1 (144), xor2 (288), xor4 (576)
        float xnE = xleaf, ynE = yleaf;
        xnE = xnE + __shfl_xor(xnE, 1, 16);
        xnE = xnE + __shfl_xor(xnE, 2, 16);
        xnE = xnE + __shfl_xor(xnE, 4, 16);
        ynE = ynE + __shfl_xor(ynE, 1, 16);
        ynE = ynE + __shfl_xor(ynE, 2, 16);
        ynE = ynE + __shfl_xor(ynE, 4, 16);

        if (j == 0) {
            float t0 = -2.0f * E;      // exact (scale by 2)
            float k1 = t0 + ynE;
            float k2 = k1 + xnE;
            keyEmu[cand] = k2 + 1e-5f; // Dw = D + 1e-5 in f32
        }
    }
    __syncthreads();

    // sort 16 by (emulated key asc, window index asc) -> top-5
    if (tid == 0) {
        float d[NSEL]; int w[NSEL];
        for (int i = 0; i < NSEL; i++) { d[i] = keyEmu[i]; w[i] = topW[i]; }
        for (int a = 1; a < NSEL; a++) {
            float dv = d[a]; int wv = w[a]; int p = a - 1;
            while (p >= 0 && (d[p] > dv || (d[p] == dv && w[p] > wv))) {
                d[p + 1] = d[p]; w[p + 1] = w[p]; p--;
            }
            d[p + 1] = dv; w[p + 1] = wv;
        }
        for (int i = 0; i < KK; i++) { selKey[i] = d[i]; selW[i] = w[i]; }
    }
    __syncthreads();

    if (tid < KK) {
        int w = selW[tid];
        int cwi = w / WIN, cwj = w % WIN;
        int n = (si + cwi) * M1 + (sj + cwj);
        out_idx[(b * NP + m) * KK + tid] = (float)n;
        float s10 = selKey[tid] / 10.0f;           // f32 divide, as np
        double sv = exp(-(double)s10);
        sv_ws[(b * KK + tid) * NP + m] = (float)sv;
    }

    // per-channel L1 sums for the 5 winners
    for (int pair = tid; pair < KK * C_; pair += 256) {
        int k = pair >> 6, c = pair & 63;
        int w = selW[k];
        int px = si + w / WIN, py = sj + w % WIN;
        float acc = 0.f;
        #pragma unroll
        for (int p = 0; p < 9; p++) {
            acc += fabsf(ys[p * 64 + c]
                       - xe[((b * C_ + c) * H_ + px + p / 3) * W_ + py + p % 3]);
        }
        dsum_ws[((b * KK + k) * C_ + c) * NP + m] = acc;
    }
}

// overlap-add of 6x6 constant patches, stride 2 -> each pixel sums <=9 patches
__device__ __forceinline__ void oa_range(int y, int& r0, int& r1) {
    r0 = (y >= 5) ? ((y - 4) >> 1) : 0;
    r1 = min(M1 - 1, y >> 1);
}

__global__ __launch_bounds__(256) void score_img_kernel(const float* __restrict__ sv_ws,
                                                        float* __restrict__ out) {
    int idx = blockIdx.x * 256 + threadIdx.x;
    if (idx >= OUT_SCORE_SZ) return;
    int x = idx & 127, y = (idx >> 7) & 127;
    int bk = idx >> 14;  // b*5+k
    int r0, r1, s0, s1;
    oa_range(y, r0, r1);
    oa_range(x, s0, s1);
    const float* base = sv_ws + bk * NP;
    float acc = 0.f;
    for (int rr = r0; rr <= r1; rr++)
        for (int ss = s0; ss <= s1; ss++)
            acc += base[rr * M1 + ss];
    out[idx] = acc;
}

__global__ __launch_bounds__(256) void diff_img_kernel(const float* __restrict__ dsum_ws,
                                                       float* __restrict__ out) {
    int idx = blockIdx.x * 256 + threadIdx.x;
    if (idx >= OUT_DIFF_SZ) return;
    int x = idx & 127, y = (idx >> 7) & 127;
    int bkc = idx >> 14;           // [0,640): b*320 + k*64 + c
    int r0, r1, s0, s1;
    oa_range(y, r0, r1);
    oa_range(x, s0, s1);
    const float* base = dsum_ws + bkc * NP;
    float acc = 0.f;
    for (int rr = r0; rr <= r1; rr++)
        for (int ss = s0; ss <= s1; ss++)
            acc += base[rr * M1 + ss];
    out[idx] = acc;
}

extern "C" void kernel_launch(void* const* d_in, const int* in_sizes, int n_in,
                              void* d_out, int out_size, void* d_ws, size_t ws_size,
                              hipStream_t stream) {
    const float* xe = (const float*)d_in[0];
    const float* ye = (const float*)d_in[1];
    float* out = (float*)d_out;
    float* ws = (float*)d_ws;

    float* xn      = ws + WS_XNORM;
    float* sv_ws   = ws + WS_SV;
    float* dsum_ws = ws + WS_DSUM;

    xnorm_kernel<<<(B_ * NP + 255) / 256, 256, 0, stream>>>(xe, xn);
    knn_kernel<<<B_ * NP, 256, 0, stream>>>(xe, ye, xn,
                                            out + OUT_IDX_OFF, sv_ws, dsum_ws);
    score_img_kernel<<<OUT_SCORE_SZ / 256, 256, 0, stream>>>(sv_ws, out);
    diff_img_kernel<<<OUT_DIFF_SZ / 256, 256, 0, stream>>>(dsum_ws, out + OUT_DIFF_OFF);
}

// Round 6
// 362.836 us; speedup vs baseline: 2.8622x; 2.8622x over previous
//
#include <hip/hip_runtime.h>
#include <float.h>
#include <math.h>

#define B_ 2
#define C_ 64
#define HW 64
#define M1 62
#define NP (M1*M1)      // 3844
#define WIN 30
#define KK 5
#define NSEL 16
#define HS 128

#define OUT_SCORE_SZ (B_*KK*HS*HS)       // 163840
#define OUT_IDX_OFF  (OUT_SCORE_SZ)
#define OUT_IDX_SZ   (B_*NP*KK)          // 38440
#define OUT_DIFF_OFF (OUT_IDX_OFF+OUT_IDX_SZ)
#define OUT_DIFF_SZ  (B_*KK*C_*HS*HS)    // 10485760

// ws layout in floats
#define WS_XNP 0                          // B_*NP = 7688 (pad 8192)
#define WS_YNP 8192
#define WS_TOP 16384                      // ints: B_*NP*16 = 123008
#define WS_SV  (16384+123008)             // 139392, B_*KK*NP = 38440 (pad 40960)
#define WS_DSUM (139392+40960)            // 180352, B_*KK*C_*NP = 2460160

typedef __attribute__((ext_vector_type(8))) short bf16x8;
typedef __attribute__((ext_vector_type(4))) float f32x4;

__device__ __forceinline__ unsigned short f2bf(float f) {
    union { float f; unsigned int u; } v; v.f = f;
    unsigned int r = (v.u + 0x7FFFu + ((v.u >> 16) & 1u)) >> 16;
    return (unsigned short)r;
}

// ---------------- K1: numpy-pairwise norms (bitwise np emulation) ------------
// pairwise_sum(576) = ((L0+L1)+(L2+L3))+((L4+L5)+(L6+L7)), leaf=72 scalar 8-acc.
// 8 lanes per patch; verified structure from the passing round-5 kernel.
__global__ __launch_bounds__(256) void norm_np_kernel(const float* __restrict__ xe,
                                                      const float* __restrict__ ye,
                                                      float* __restrict__ xnp,
                                                      float* __restrict__ ynp) {
    int gid = blockIdx.x * 256 + threadIdx.x;
    if (gid >= 2 * B_ * NP * 8) return;
    int which = gid / (B_ * NP * 8);
    int rem = gid - which * (B_ * NP * 8);
    int patch = rem >> 3, leaf = rem & 7;
    int b = patch / NP, m = patch - b * NP;
    int r = m / M1, s = m - r * M1;
    const float* src = (which ? ye : xe) + (size_t)b * C_ * HW * HW;

    int base = leaf * 72;
    float a8[8];
    #pragma unroll
    for (int i = 0; i < 8; i++) {
        int e = base + i; int c = e / 9, p = e - c * 9;
        float v = src[(c * HW + r + p / 3) * HW + s + p % 3];
        a8[i] = v * v;
    }
    for (int i0 = 8; i0 < 72; i0 += 8) {
        #pragma unroll
        for (int i = 0; i < 8; i++) {
            int e = base + i0 + i; int c = e / 9, p = e - c * 9;
            float v = src[(c * HW + r + p / 3) * HW + s + p % 3];
            a8[i] += v * v;
        }
    }
    float t = ((a8[0] + a8[1]) + (a8[2] + a8[3])) + ((a8[4] + a8[5]) + (a8[6] + a8[7]));
    t = t + __shfl_xor(t, 1, 8);
    t = t + __shfl_xor(t, 2, 8);
    t = t + __shfl_xor(t, 4, 8);
    if (leaf == 0) (which ? ynp : xnp)[patch] = t;
}

// ---------------- K2: MFMA prescreen + wave-level top-16 --------------------
#define UC 33
#define UPR 35
#define UPC 40
#define CSTR 40      // bf16 channel stride (32 + 8 pad): 80B, 16B-aligned groups
#define YSTR 584     // 576 + 8 pad

#define XS_BYTES (UPR*UPC*CSTR*2)         // 112000
#define YS_OFFB  XS_BYTES                  // 112000
#define XN_OFFB  (YS_OFFB + 16*YSTR*2)     // 130688
#define SM_BYTES (XN_OFFB + 1089*4 + 16)   // 135060

__global__ __launch_bounds__(512) void gemm_select_kernel(const float* __restrict__ xe,
                                                          const float* __restrict__ ye,
                                                          const float* __restrict__ xnp,
                                                          int* __restrict__ top_ws) {
    __shared__ __align__(16) unsigned char smem[SM_BYTES];
    short* xsS = (short*)smem;
    unsigned int* xsW = (unsigned int*)smem;
    short* ysS = (short*)(smem + YS_OFFB);
    float* xnL = (float*)(smem + XN_OFFB);
    float* Dl  = (float*)smem;            // reuses xs region after MFMA

    const int bid = blockIdx.x;
    const int b  = bid >> 8;
    const int t  = bid & 255;
    const int r0 = (t >> 4) * 4;
    const int s0 = (t & 15) * 4;
    const int u0r = min(max(r0 - 15, 0), 32);
    const int u0c = min(max(s0 - 15, 0), 32);
    const int g0c = min(u0c & ~3, 24);    // aligned staged col origin (40 cols fit in 64)
    const int cofs = u0c - g0c;
    const int tid = threadIdx.x;
    const int l   = tid & 63;
    const int wid = tid >> 6;             // 0..7
    const int lq  = l & 15;
    const int kg  = l >> 4;               // 0..3

    // stage y patches (bf16, e = p*64+c) and xn for the candidate union
    for (int i = tid; i < 16 * 576; i += 512) {
        int q = i / 576, e = i - q * 576;
        int p = e >> 6, c = e & 63;
        int rq = min(r0 + (q >> 2), 61), sq = min(s0 + (q & 3), 61);
        float v = ye[((b * C_ + c) * HW + rq + p / 3) * HW + sq + p % 3];
        ysS[q * YSTR + e] = (short)f2bf(v);
    }
    for (int i = tid; i < 1089; i += 512) {
        int cr = i / 33, cc = i - cr * 33;
        int nr = min(u0r + cr, 61), nc = min(u0c + cc, 61);
        xnL[i] = xnp[b * NP + nr * M1 + nc];
    }

    f32x4 acc[9];
    #pragma unroll
    for (int i = 0; i < 9; i++) acc[i] = (f32x4){0.f, 0.f, 0.f, 0.f};

    int prb[9], pcb[9];
    #pragma unroll
    for (int i = 0; i < 9; i++) {
        int ci = (wid * 9 + i) * 16 + lq;  // 0..1151 (phantom beyond 1088 masked later)
        int cr = ci / 33;
        prb[i] = cr;
        pcb[i] = ci - cr * 33 + cofs;
    }

    for (int ch = 0; ch < 2; ch++) {
        __syncthreads();
        // stage 32-channel half of the pixel union, bf16 channel-last
        for (int u = tid; u < 16 * 35; u += 512) {
            int cp = u / 35, a = u - cp * 35;
            int c0 = ch * 32 + cp * 2;
            int gr = min(u0r + a, 63);
            const float4* pa = (const float4*)(xe + ((size_t)(b * C_ + c0) * HW + gr) * HW + g0c);
            const float4* pb = (const float4*)(xe + ((size_t)(b * C_ + c0 + 1) * HW + gr) * HW + g0c);
            #pragma unroll
            for (int blk = 0; blk < 10; blk++) {
                float4 va = pa[blk], vb = pb[blk];
                int w0 = (a * UPC + blk * 4) * (CSTR / 2) + cp;  // u32 word index
                xsW[w0            ] = (unsigned)f2bf(va.x) | ((unsigned)f2bf(vb.x) << 16);
                xsW[w0 + CSTR / 2 ] = (unsigned)f2bf(va.y) | ((unsigned)f2bf(vb.y) << 16);
                xsW[w0 + CSTR     ] = (unsigned)f2bf(va.z) | ((unsigned)f2bf(vb.z) << 16);
                xsW[w0 + 3*CSTR/2 ] = (unsigned)f2bf(va.w) | ((unsigned)f2bf(vb.w) << 16);
            }
        }
        __syncthreads();
        #pragma unroll
        for (int p = 0; p < 9; p++) {
            const int pi = p / 3, pj = p % 3;
            bf16x8 af = *(const bf16x8*)(ysS + lq * YSTR + p * 64 + ch * 32 + kg * 8);
            #pragma unroll
            for (int i = 0; i < 9; i++) {
                const short* bp = xsS + ((prb[i] + pi) * UPC + (pcb[i] + pj)) * CSTR + kg * 8;
                bf16x8 bf = *(const bf16x8*)bp;
                acc[i] = __builtin_amdgcn_mfma_f32_16x16x32_bf16(af, bf, acc[i], 0, 0, 0);
            }
        }
    }

    __syncthreads();
    // epilogue: D = xn - 2*dot into Dl[q][ci] (C layout: col=lane&15, row=(lane>>4)*4+reg)
    #pragma unroll
    for (int i = 0; i < 9; i++) {
        int ci = (wid * 9 + i) * 16 + lq;
        if (ci < 1089) {
            float xnv = xnL[ci];
            #pragma unroll
            for (int j = 0; j < 4; j++) {
                Dl[(kg * 4 + j) * 1089 + ci] = xnv - 2.0f * acc[i][j];
            }
        }
    }
    __syncthreads();

    // wave-level top-16 per query (no barriers), 2 queries per wave
    for (int qq = 0; qq < 2; qq++) {
        int q = wid * 2 + qq;
        int rq = r0 + (q >> 2), sq = s0 + (q & 3);
        if (rq > 61 || sq > 61) continue;
        int siq = min(max(rq - 15, 0), 32);
        int sjq = min(max(sq - 15, 0), 32);
        int ro = siq - u0r, co = sjq - u0c;
        float kv[15]; int wv[15];
        #pragma unroll
        for (int kk = 0; kk < 15; kk++) {
            int w = kk * 64 + l;
            if (w < 900) {
                int wi = w / 30, wj = w - wi * 30;
                kv[kk] = Dl[q * 1089 + (ro + wi) * 33 + (co + wj)];
                wv[kk] = w;
            } else { kv[kk] = FLT_MAX; wv[kk] = 1 << 30; }
        }
        int obase = (b * NP + rq * M1 + sq) * NSEL;
        for (int it = 0; it < NSEL; it++) {
            float bk = FLT_MAX; int bw = 1 << 30;
            #pragma unroll
            for (int kk = 0; kk < 15; kk++)
                if (kv[kk] < bk || (kv[kk] == bk && wv[kk] < bw)) { bk = kv[kk]; bw = wv[kk]; }
            #pragma unroll
            for (int off = 32; off >= 1; off >>= 1) {
                float ok = __shfl_xor(bk, off);
                int   ow = __shfl_xor(bw, off);
                if (ok < bk || (ok == bk && ow < bw)) { bk = ok; bw = ow; }
            }
            #pragma unroll
            for (int kk = 0; kk < 15; kk++)
                if (wv[kk] == bw) kv[kk] = FLT_MAX;
            if (l == 0) {
                int wi = bw / 30, wj = bw - wi * 30;
                top_ws[obase + it] = (siq + wi) * M1 + (sjq + wj);
            }
        }
    }
}

// ---------------- K3: bitwise np-f32 emulation + outputs --------------------
__global__ __launch_bounds__(256) void emu_kernel(const float* __restrict__ xe,
                                                  const float* __restrict__ ye,
                                                  const float* __restrict__ xnp,
                                                  const float* __restrict__ ynp,
                                                  const int* __restrict__ top_ws,
                                                  float* __restrict__ out_idx,
                                                  float* __restrict__ sv_ws,
                                                  float* __restrict__ dsum_ws) {
    __shared__ float ysP[576], ysE[576];
    __shared__ int topWs[NSEL];
    __shared__ float keyEmu[NSEL];
    __shared__ float selKey[KK];
    __shared__ int   selN[KK];

    const int bid = blockIdx.x;
    const int b = bid / NP, m = bid - b * NP;
    const int r = m / M1, s = m - r * M1;
    const int tid = threadIdx.x;

    for (int t = tid; t < 576; t += 256) {
        int p = t >> 6, c = t & 63;
        float v = ye[((b * C_ + c) * HW + r + p / 3) * HW + s + p % 3];
        ysP[t] = v;
        ysE[c * 9 + p] = v;
    }
    if (tid < NSEL) topWs[tid] = top_ws[bid * NSEL + tid];
    __syncthreads();

    {   // einsum E emulation: AVX512 single-vaccum nested-FMA, lane j owns e≡j (mod 16)
        const int cand = tid >> 4, j = tid & 15;
        const int n = topWs[cand];
        const int px = n / M1, py = n - px * M1;
        const float* xb = xe + (size_t)b * C_ * HW * HW;
        float acc = 0.f;
        #pragma unroll
        for (int t = 0; t < 36; t++) {
            int e = t * 16 + j;
            int c = e / 9, p = e - c * 9;
            float xv = xb[(c * HW + px + p / 3) * HW + py + p % 3];
            acc = fmaf(ysE[e], xv, acc);
        }
        float E = acc;
        E = E + __shfl_xor(E, 8, 16);
        E = E + __shfl_xor(E, 4, 16);
        E = E + __shfl_xor(E, 2, 16);
        E = E + __shfl_xor(E, 1, 16);
        if (j == 0) {
            float t0 = -2.0f * E;
            float k1 = t0 + ynp[b * NP + m];
            float k2 = k1 + xnp[b * NP + n];
            keyEmu[cand] = k2 + 1e-5f;
        }
    }
    __syncthreads();

    if (tid == 0) {
        float d[NSEL]; int w[NSEL];
        for (int i = 0; i < NSEL; i++) { d[i] = keyEmu[i]; w[i] = topWs[i]; }
        for (int a = 1; a < NSEL; a++) {
            float dv = d[a]; int wv2 = w[a]; int p = a - 1;
            while (p >= 0 && (d[p] > dv || (d[p] == dv && w[p] > wv2))) {
                d[p + 1] = d[p]; w[p + 1] = w[p]; p--;
            }
            d[p + 1] = dv; w[p + 1] = wv2;
        }
        for (int i = 0; i < KK; i++) { selKey[i] = d[i]; selN[i] = w[i]; }
    }
    __syncthreads();

    if (tid < KK) {
        out_idx[(b * NP + m) * KK + tid] = (float)selN[tid];
        float s10 = selKey[tid] / 10.0f;
        double sv = exp(-(double)s10);
        sv_ws[(b * KK + tid) * NP + m] = (float)sv;
    }

    for (int pair = tid; pair < KK * C_; pair += 256) {
        int k = pair >> 6, c = pair & 63;
        int n = selN[k];
        int px = n / M1, py = n - px * M1;
        float a = 0.f;
        #pragma unroll
        for (int p = 0; p < 9; p++) {
            a += fabsf(ysP[p * 64 + c]
                     - xe[((b * C_ + c) * HW + px + p / 3) * HW + py + p % 3]);
        }
        dsum_ws[((b * KK + k) * C_ + c) * NP + m] = a;
    }
}

// ---------------- overlap-add image kernels (unchanged) ---------------------
__device__ __forceinline__ void oa_range(int y, int& r0, int& r1) {
    r0 = (y >= 5) ? ((y - 4) >> 1) : 0;
    r1 = min(M1 - 1, y >> 1);
}

__global__ __launch_bounds__(256) void score_img_kernel(const float* __restrict__ sv_ws,
                                                        float* __restrict__ out) {
    int idx = blockIdx.x * 256 + threadIdx.x;
    if (idx >= OUT_SCORE_SZ) return;
    int x = idx & 127, y = (idx >> 7) & 127;
    int bk = idx >> 14;
    int r0, r1, s0, s1;
    oa_range(y, r0, r1);
    oa_range(x, s0, s1);
    const float* base = sv_ws + bk * NP;
    float acc = 0.f;
    for (int rr = r0; rr <= r1; rr++)
        for (int ss = s0; ss <= s1; ss++)
            acc += base[rr * M1 + ss];
    out[idx] = acc;
}

__global__ __launch_bounds__(256) void diff_img_kernel(const float* __restrict__ dsum_ws,
                                                       float* __restrict__ out) {
    int idx = blockIdx.x * 256 + threadIdx.x;
    if (idx >= OUT_DIFF_SZ) return;
    int x = idx & 127, y = (idx >> 7) & 127;
    int bkc = idx >> 14;
    int r0, r1, s0, s1;
    oa_range(y, r0, r1);
    oa_range(x, s0, s1);
    const float* base = dsum_ws + bkc * NP;
    float acc = 0.f;
    for (int rr = r0; rr <= r1; rr++)
        for (int ss = s0; ss <= s1; ss++)
            acc += base[rr * M1 + ss];
    out[idx] = acc;
}

extern "C" void kernel_launch(void* const* d_in, const int* in_sizes, int n_in,
                              void* d_out, int out_size, void* d_ws, size_t ws_size,
                              hipStream_t stream) {
    const float* xe = (const float*)d_in[0];
    const float* ye = (const float*)d_in[1];
    float* out = (float*)d_out;
    float* ws = (float*)d_ws;

    float* xnp = ws + WS_XNP;
    float* ynp = ws + WS_YNP;
    int*   topw = (int*)(ws + WS_TOP);
    float* sv_ws = ws + WS_SV;
    float* dsum_ws = ws + WS_DSUM;

    norm_np_kernel<<<(2 * B_ * NP * 8 + 255) / 256, 256, 0, stream>>>(xe, ye, xnp, ynp);
    gemm_select_kernel<<<2 * 256, 512, 0, stream>>>(xe, ye, xnp, topw);
    emu_kernel<<<B_ * NP, 256, 0, stream>>>(xe, ye, xnp, ynp, topw,
                                            out + OUT_IDX_OFF, sv_ws, dsum_ws);
    score_img_kernel<<<OUT_SCORE_SZ / 256, 256, 0, stream>>>(sv_ws, out);
    diff_img_kernel<<<OUT_DIFF_SZ / 256, 256, 0, stream>>>(dsum_ws, out + OUT_DIFF_OFF);
}

// Round 7
// 338.756 us; speedup vs baseline: 3.0657x; 1.0711x over previous
//
#include <hip/hip_runtime.h>
#include <float.h>
#include <math.h>

#define B_ 2
#define C_ 64
#define HW 64
#define M1 62
#define NP (M1*M1)      // 3844
#define WIN 30
#define KK 5
#define NSEL 16
#define HS 128

#define OUT_SCORE_SZ (B_*KK*HS*HS)       // 163840
#define OUT_IDX_OFF  (OUT_SCORE_SZ)
#define OUT_IDX_SZ   (B_*NP*KK)          // 38440
#define OUT_DIFF_OFF (OUT_IDX_OFF+OUT_IDX_SZ)
#define OUT_DIFF_SZ  (B_*KK*C_*HS*HS)    // 10485760

// ws layout in floats
#define WS_XNP 0                          // B_*NP = 7688 (pad 8192)
#define WS_YNP 8192
#define WS_TOP 16384                      // ints: B_*NP*16 = 123008
#define WS_SV  (16384+123008)             // 139392, B_*KK*NP = 38440 (pad 40960)
#define WS_DSUM (139392+40960)            // 180352, B_*KK*C_*NP = 2460160

typedef __attribute__((ext_vector_type(8))) short bf16x8;
typedef __attribute__((ext_vector_type(4))) float f32x4;

__device__ __forceinline__ unsigned short f2bf(float f) {
    union { float f; unsigned int u; } v; v.f = f;
    unsigned int r = (v.u + 0x7FFFu + ((v.u >> 16) & 1u)) >> 16;
    return (unsigned short)r;
}

// ---------------- K1: numpy-pairwise norms (bitwise np emulation) ------------
// pairwise_sum(576) = ((L0+L1)+(L2+L3))+((L4+L5)+(L6+L7)), leaf=72 scalar 8-acc.
// 8 lanes per patch. tab[e] = geometric offset of element e (c*9+p order).
__global__ __launch_bounds__(256) void norm_np_kernel(const float* __restrict__ xe,
                                                      const float* __restrict__ ye,
                                                      float* __restrict__ xnp,
                                                      float* __restrict__ ynp) {
    __shared__ int tab[576];
    for (int t = threadIdx.x; t < 576; t += 256) {
        int c = t / 9, p = t - c * 9;
        tab[t] = c * (HW * HW) + (p / 3) * HW + (p % 3);
    }
    __syncthreads();

    int gid = blockIdx.x * 256 + threadIdx.x;
    if (gid >= 2 * B_ * NP * 8) return;
    int which = gid / (B_ * NP * 8);
    int rem = gid - which * (B_ * NP * 8);
    int patch = rem >> 3, leaf = rem & 7;
    int b = patch / NP, m = patch - b * NP;
    int r = m / M1, s = m - r * M1;
    const float* src = (which ? ye : xe) + (size_t)b * C_ * HW * HW + r * HW + s;

    int base = leaf * 72;
    float a8[8];
    #pragma unroll
    for (int i = 0; i < 8; i++) {
        float v = src[tab[base + i]];
        a8[i] = v * v;
    }
    for (int i0 = 8; i0 < 72; i0 += 8) {
        #pragma unroll
        for (int i = 0; i < 8; i++) {
            float v = src[tab[base + i0 + i]];
            a8[i] += v * v;
        }
    }
    float t = ((a8[0] + a8[1]) + (a8[2] + a8[3])) + ((a8[4] + a8[5]) + (a8[6] + a8[7]));
    t = t + __shfl_xor(t, 1, 8);
    t = t + __shfl_xor(t, 2, 8);
    t = t + __shfl_xor(t, 4, 8);
    if (leaf == 0) (which ? ynp : xnp)[patch] = t;
}

// ---------------- K2: MFMA prescreen + wave-level top-16 --------------------
#define UC 33
#define UPR 35
#define UPC 40
#define CSTR 40      // bf16 channel stride (32 + 8 pad): 80B, 16B-aligned groups
#define YSTR 584     // 576 + 8 pad

#define XS_BYTES (UPR*UPC*CSTR*2)         // 112000
#define YS_OFFB  XS_BYTES                  // 112000
#define XN_OFFB  (YS_OFFB + 16*YSTR*2)     // 130688
#define SM_BYTES (XN_OFFB + 1089*4 + 16)   // 135060

__global__ __launch_bounds__(512) void gemm_select_kernel(const float* __restrict__ xe,
                                                          const float* __restrict__ ye,
                                                          const float* __restrict__ xnp,
                                                          int* __restrict__ top_ws) {
    __shared__ __align__(16) unsigned char smem[SM_BYTES];
    short* xsS = (short*)smem;
    unsigned int* xsW = (unsigned int*)smem;
    short* ysS = (short*)(smem + YS_OFFB);
    float* xnL = (float*)(smem + XN_OFFB);
    float* Dl  = (float*)smem;            // reuses xs region after MFMA

    const int bid = blockIdx.x;
    const int b  = bid >> 8;
    const int t  = bid & 255;
    const int r0 = (t >> 4) * 4;
    const int s0 = (t & 15) * 4;
    const int u0r = min(max(r0 - 15, 0), 32);
    const int u0c = min(max(s0 - 15, 0), 32);
    const int g0c = min(u0c & ~3, 24);    // aligned staged col origin (40 cols fit in 64)
    const int cofs = u0c - g0c;
    const int tid = threadIdx.x;
    const int l   = tid & 63;
    const int wid = tid >> 6;             // 0..7
    const int lq  = l & 15;
    const int kg  = l >> 4;               // 0..3

    // stage y patches (bf16, e = p*64+c) and xn for the candidate union
    for (int i = tid; i < 16 * 576; i += 512) {
        int q = i / 576, e = i - q * 576;
        int p = e >> 6, c = e & 63;
        int rq = min(r0 + (q >> 2), 61), sq = min(s0 + (q & 3), 61);
        float v = ye[((b * C_ + c) * HW + rq + p / 3) * HW + sq + p % 3];
        ysS[q * YSTR + e] = (short)f2bf(v);
    }
    for (int i = tid; i < 1089; i += 512) {
        int cr = i / 33, cc = i - cr * 33;
        int nr = min(u0r + cr, 61), nc = min(u0c + cc, 61);
        xnL[i] = xnp[b * NP + nr * M1 + nc];
    }

    f32x4 acc[9];
    #pragma unroll
    for (int i = 0; i < 9; i++) acc[i] = (f32x4){0.f, 0.f, 0.f, 0.f};

    int prb[9], pcb[9];
    #pragma unroll
    for (int i = 0; i < 9; i++) {
        int ci = (wid * 9 + i) * 16 + lq;  // 0..1151 (phantom beyond 1088 masked later)
        int cr = ci / 33;
        prb[i] = cr;
        pcb[i] = ci - cr * 33 + cofs;
    }

    for (int ch = 0; ch < 2; ch++) {
        __syncthreads();
        // stage 32-channel half of the pixel union, bf16 channel-last
        for (int u = tid; u < 16 * 35; u += 512) {
            int cp = u / 35, a = u - cp * 35;
            int c0 = ch * 32 + cp * 2;
            int gr = min(u0r + a, 63);
            const float4* pa = (const float4*)(xe + ((size_t)(b * C_ + c0) * HW + gr) * HW + g0c);
            const float4* pb = (const float4*)(xe + ((size_t)(b * C_ + c0 + 1) * HW + gr) * HW + g0c);
            #pragma unroll
            for (int blk = 0; blk < 10; blk++) {
                float4 va = pa[blk], vb = pb[blk];
                int w0 = (a * UPC + blk * 4) * (CSTR / 2) + cp;  // u32 word index
                xsW[w0            ] = (unsigned)f2bf(va.x) | ((unsigned)f2bf(vb.x) << 16);
                xsW[w0 + CSTR / 2 ] = (unsigned)f2bf(va.y) | ((unsigned)f2bf(vb.y) << 16);
                xsW[w0 + CSTR     ] = (unsigned)f2bf(va.z) | ((unsigned)f2bf(vb.z) << 16);
                xsW[w0 + 3*CSTR/2 ] = (unsigned)f2bf(va.w) | ((unsigned)f2bf(vb.w) << 16);
            }
        }
        __syncthreads();
        #pragma unroll
        for (int p = 0; p < 9; p++) {
            const int pi = p / 3, pj = p % 3;
            bf16x8 af = *(const bf16x8*)(ysS + lq * YSTR + p * 64 + ch * 32 + kg * 8);
            #pragma unroll
            for (int i = 0; i < 9; i++) {
                const short* bp = xsS + ((prb[i] + pi) * UPC + (pcb[i] + pj)) * CSTR + kg * 8;
                bf16x8 bf = *(const bf16x8*)bp;
                acc[i] = __builtin_amdgcn_mfma_f32_16x16x32_bf16(af, bf, acc[i], 0, 0, 0);
            }
        }
    }

    __syncthreads();
    // epilogue: D = xn - 2*dot into Dl[q][ci] (C layout: col=lane&15, row=(lane>>4)*4+reg)
    #pragma unroll
    for (int i = 0; i < 9; i++) {
        int ci = (wid * 9 + i) * 16 + lq;
        if (ci < 1089) {
            float xnv = xnL[ci];
            #pragma unroll
            for (int j = 0; j < 4; j++) {
                Dl[(kg * 4 + j) * 1089 + ci] = xnv - 2.0f * acc[i][j];
            }
        }
    }
    __syncthreads();

    // wave-level top-16 per query (no barriers), 2 queries per wave
    for (int qq = 0; qq < 2; qq++) {
        int q = wid * 2 + qq;
        int rq = r0 + (q >> 2), sq = s0 + (q & 3);
        if (rq > 61 || sq > 61) continue;
        int siq = min(max(rq - 15, 0), 32);
        int sjq = min(max(sq - 15, 0), 32);
        int ro = siq - u0r, co = sjq - u0c;
        float kv[15]; int wv[15];
        #pragma unroll
        for (int kk = 0; kk < 15; kk++) {
            int w = kk * 64 + l;
            if (w < 900) {
                int wi = w / 30, wj = w - wi * 30;
                kv[kk] = Dl[q * 1089 + (ro + wi) * 33 + (co + wj)];
                wv[kk] = w;
            } else { kv[kk] = FLT_MAX; wv[kk] = 1 << 30; }
        }
        int obase = (b * NP + rq * M1 + sq) * NSEL;
        for (int it = 0; it < NSEL; it++) {
            float bk = FLT_MAX; int bw = 1 << 30;
            #pragma unroll
            for (int kk = 0; kk < 15; kk++)
                if (kv[kk] < bk || (kv[kk] == bk && wv[kk] < bw)) { bk = kv[kk]; bw = wv[kk]; }
            #pragma unroll
            for (int off = 32; off >= 1; off >>= 1) {
                float ok = __shfl_xor(bk, off);
                int   ow = __shfl_xor(bw, off);
                if (ok < bk || (ok == bk && ow < bw)) { bk = ok; bw = ow; }
            }
            #pragma unroll
            for (int kk = 0; kk < 15; kk++)
                if (wv[kk] == bw) kv[kk] = FLT_MAX;
            if (l == 0) {
                int wi = bw / 30, wj = bw - wi * 30;
                top_ws[obase + it] = (siq + wi) * M1 + (sjq + wj);
            }
        }
    }
}

// ---------------- K3: bitwise np-f32 emulation + outputs --------------------
// Address-table version: tab[e] = c*4096 + (p/3)*64 + p%3 (e = c*9+p), so each
// scattered load is ds_read(tab) + v_add + global_load. Float ops unchanged ->
// bit-identical keys.
__global__ __launch_bounds__(256) void emu_kernel(const float* __restrict__ xe,
                                                  const float* __restrict__ ye,
                                                  const float* __restrict__ xnp,
                                                  const float* __restrict__ ynp,
                                                  const int* __restrict__ top_ws,
                                                  float* __restrict__ out_idx,
                                                  float* __restrict__ sv_ws,
                                                  float* __restrict__ dsum_ws) {
    __shared__ float ysP[576], ysE[576];
    __shared__ int tab[576];
    __shared__ int topWs[NSEL];
    __shared__ float keyEmu[NSEL];
    __shared__ float selKey[KK];
    __shared__ int   selN[KK];

    const int bid = blockIdx.x;
    const int b = bid / NP, m = bid - b * NP;
    const int r = m / M1, s = m - r * M1;
    const int tid = threadIdx.x;
    const float* xb = xe + (size_t)b * C_ * HW * HW;
    const float* yb = ye + (size_t)b * C_ * HW * HW + r * HW + s;

    for (int t = tid; t < 576; t += 256) {
        int c = t / 9, p = t - c * 9;
        tab[t] = c * (HW * HW) + (p / 3) * HW + (p % 3);
    }
    if (tid < NSEL) topWs[tid] = top_ws[bid * NSEL + tid];
    __syncthreads();

    // stage y patch via tab (t is e-order); also scatter to p-order for dsum
    for (int t = tid; t < 576; t += 256) {
        float v = yb[tab[t]];
        ysE[t] = v;
        int c = t / 9, p = t - c * 9;
        ysP[p * 64 + c] = v;
    }
    __syncthreads();

    {   // einsum E emulation: AVX512 single-vaccum nested-FMA, lane j owns e≡j (mod 16)
        const int cand = tid >> 4, j = tid & 15;
        const int n = topWs[cand];
        const int px = n / M1, py = n - px * M1;
        const float* xp = xb + px * HW + py;
        float acc = 0.f;
        #pragma unroll
        for (int t = 0; t < 36; t++) {
            int e = t * 16 + j;
            acc = fmaf(ysE[e], xp[tab[e]], acc);
        }
        float E = acc;
        E = E + __shfl_xor(E, 8, 16);
        E = E + __shfl_xor(E, 4, 16);
        E = E + __shfl_xor(E, 2, 16);
        E = E + __shfl_xor(E, 1, 16);
        if (j == 0) {
            float t0 = -2.0f * E;
            float k1 = t0 + ynp[b * NP + m];
            float k2 = k1 + xnp[b * NP + n];
            keyEmu[cand] = k2 + 1e-5f;
        }
    }
    __syncthreads();

    if (tid == 0) {
        float d[NSEL]; int w[NSEL];
        for (int i = 0; i < NSEL; i++) { d[i] = keyEmu[i]; w[i] = topWs[i]; }
        for (int a = 1; a < NSEL; a++) {
            float dv = d[a]; int wv2 = w[a]; int p = a - 1;
            while (p >= 0 && (d[p] > dv || (d[p] == dv && w[p] > wv2))) {
                d[p + 1] = d[p]; w[p + 1] = w[p]; p--;
            }
            d[p + 1] = dv; w[p + 1] = wv2;
        }
        for (int i = 0; i < KK; i++) { selKey[i] = d[i]; selN[i] = w[i]; }
    }
    __syncthreads();

    if (tid < KK) {
        out_idx[(b * NP + m) * KK + tid] = (float)selN[tid];
        float s10 = selKey[tid] / 10.0f;
        double sv = exp(-(double)s10);
        sv_ws[(b * KK + tid) * NP + m] = (float)sv;
    }

    for (int pair = tid; pair < KK * C_; pair += 256) {
        int k = pair >> 6, c = pair & 63;
        int n = selN[k];
        int px = n / M1, py = n - px * M1;
        const float* xp = xb + c * (HW * HW) + px * HW + py;
        float a = 0.f;
        #pragma unroll
        for (int pi = 0; pi < 3; pi++) {
            #pragma unroll
            for (int pj = 0; pj < 3; pj++) {
                a += fabsf(ysP[(pi * 3 + pj) * 64 + c] - xp[pi * HW + pj]);
            }
        }
        dsum_ws[((b * KK + k) * C_ + c) * NP + m] = a;
    }
}

// ---------------- overlap-add image kernels (unchanged) ---------------------
__device__ __forceinline__ void oa_range(int y, int& r0, int& r1) {
    r0 = (y >= 5) ? ((y - 4) >> 1) : 0;
    r1 = min(M1 - 1, y >> 1);
}

__global__ __launch_bounds__(256) void score_img_kernel(const float* __restrict__ sv_ws,
                                                        float* __restrict__ out) {
    int idx = blockIdx.x * 256 + threadIdx.x;
    if (idx >= OUT_SCORE_SZ) return;
    int x = idx & 127, y = (idx >> 7) & 127;
    int bk = idx >> 14;
    int r0, r1, s0, s1;
    oa_range(y, r0, r1);
    oa_range(x, s0, s1);
    const float* base = sv_ws + bk * NP;
    float acc = 0.f;
    for (int rr = r0; rr <= r1; rr++)
        for (int ss = s0; ss <= s1; ss++)
            acc += base[rr * M1 + ss];
    out[idx] = acc;
}

__global__ __launch_bounds__(256) void diff_img_kernel(const float* __restrict__ dsum_ws,
                                                       float* __restrict__ out) {
    int idx = blockIdx.x * 256 + threadIdx.x;
    if (idx >= OUT_DIFF_SZ) return;
    int x = idx & 127, y = (idx >> 7) & 127;
    int bkc = idx >> 14;
    int r0, r1, s0, s1;
    oa_range(y, r0, r1);
    oa_range(x, s0, s1);
    const float* base = dsum_ws + bkc * NP;
    float acc = 0.f;
    for (int rr = r0; rr <= r1; rr++)
        for (int ss = s0; ss <= s1; ss++)
            acc += base[rr * M1 + ss];
    out[idx] = acc;
}

extern "C" void kernel_launch(void* const* d_in, const int* in_sizes, int n_in,
                              void* d_out, int out_size, void* d_ws, size_t ws_size,
                              hipStream_t stream) {
    const float* xe = (const float*)d_in[0];
    const float* ye = (const float*)d_in[1];
    float* out = (float*)d_out;
    float* ws = (float*)d_ws;

    float* xnp = ws + WS_XNP;
    float* ynp = ws + WS_YNP;
    int*   topw = (int*)(ws + WS_TOP);
    float* sv_ws = ws + WS_SV;
    float* dsum_ws = ws + WS_DSUM;

    norm_np_kernel<<<(2 * B_ * NP * 8 + 255) / 256, 256, 0, stream>>>(xe, ye, xnp, ynp);
    gemm_select_kernel<<<2 * 256, 512, 0, stream>>>(xe, ye, xnp, topw);
    emu_kernel<<<B_ * NP, 256, 0, stream>>>(xe, ye, xnp, ynp, topw,
                                            out + OUT_IDX_OFF, sv_ws, dsum_ws);
    score_img_kernel<<<OUT_SCORE_SZ / 256, 256, 0, stream>>>(sv_ws, out);
    diff_img_kernel<<<OUT_DIFF_SZ / 256, 256, 0, stream>>>(dsum_ws, out + OUT_DIFF_OFF);
}

// Round 8
// 307.270 us; speedup vs baseline: 3.3798x; 1.1025x over previous
//
#include <hip/hip_runtime.h>
#include <float.h>
#include <math.h>

#define B_ 2
#define C_ 64
#define HW 64
#define M1 62
#define NP (M1*M1)      // 3844
#define WIN 30
#define KK 5
#define NSEL 16
#define HS 128

#define OUT_SCORE_SZ (B_*KK*HS*HS)       // 163840
#define OUT_IDX_OFF  (OUT_SCORE_SZ)
#define OUT_IDX_SZ   (B_*NP*KK)          // 38440
#define OUT_DIFF_OFF (OUT_IDX_OFF+OUT_IDX_SZ)
#define OUT_DIFF_SZ  (B_*KK*C_*HS*HS)    // 10485760

// ws layout in floats
#define WS_XNP 0                          // B_*NP = 7688 (pad 8192)
#define WS_YNP 8192
#define WS_TOP 16384                      // ints: B_*NP*16 = 123008
#define WS_SV  (16384+123008)             // 139392, B_*KK*NP = 38440 (pad 40960)
#define WS_DSUM (139392+40960)            // 180352, B_*KK*C_*NP = 2460160

typedef __attribute__((ext_vector_type(8))) short bf16x8;
typedef __attribute__((ext_vector_type(4))) float f32x4;

__device__ __forceinline__ unsigned short f2bf(float f) {
    union { float f; unsigned int u; } v; v.f = f;
    unsigned int r = (v.u + 0x7FFFu + ((v.u >> 16) & 1u)) >> 16;
    return (unsigned short)r;
}

// ---------------- K1: numpy-pairwise norms (bitwise np emulation) ------------
__global__ __launch_bounds__(256) void norm_np_kernel(const float* __restrict__ xe,
                                                      const float* __restrict__ ye,
                                                      float* __restrict__ xnp,
                                                      float* __restrict__ ynp) {
    __shared__ int tab[576];
    for (int t = threadIdx.x; t < 576; t += 256) {
        int c = t / 9, p = t - c * 9;
        tab[t] = c * (HW * HW) + (p / 3) * HW + (p % 3);
    }
    __syncthreads();

    int gid = blockIdx.x * 256 + threadIdx.x;
    if (gid >= 2 * B_ * NP * 8) return;
    int which = gid / (B_ * NP * 8);
    int rem = gid - which * (B_ * NP * 8);
    int patch = rem >> 3, leaf = rem & 7;
    int b = patch / NP, m = patch - b * NP;
    int r = m / M1, s = m - r * M1;
    const float* src = (which ? ye : xe) + (size_t)b * C_ * HW * HW + r * HW + s;

    int base = leaf * 72;
    float a8[8];
    #pragma unroll
    for (int i = 0; i < 8; i++) {
        float v = src[tab[base + i]];
        a8[i] = v * v;
    }
    for (int i0 = 8; i0 < 72; i0 += 8) {
        #pragma unroll
        for (int i = 0; i < 8; i++) {
            float v = src[tab[base + i0 + i]];
            a8[i] += v * v;
        }
    }
    float t = ((a8[0] + a8[1]) + (a8[2] + a8[3])) + ((a8[4] + a8[5]) + (a8[6] + a8[7]));
    t = t + __shfl_xor(t, 1, 8);
    t = t + __shfl_xor(t, 2, 8);
    t = t + __shfl_xor(t, 4, 8);
    if (leaf == 0) (which ? ynp : xnp)[patch] = t;
}

// ---------------- K2: MFMA prescreen + wave-level top-16 --------------------
#define UPR 35
#define UPC 42       // pixel cols slots (40 staged + 2 pad): a-stride 840 words = 8 mod 32
#define CSTR 40      // bf16 channel stride (32 ch + 8 pad): 80B, 16B-aligned
#define YSTR 584     // 576 + 8 pad

#define XS_BYTES (UPR*UPC*CSTR*2)          // 117600
#define YS_OFFB  XS_BYTES                  // 117600
#define XN_OFFB  (YS_OFFB + 16*YSTR*2)     // 136288
#define SM_BYTES (XN_OFFB + 1089*4 + 16)   // 140660

__global__ __launch_bounds__(1024) void gemm_select_kernel(const float* __restrict__ xe,
                                                           const float* __restrict__ ye,
                                                           const float* __restrict__ xnp,
                                                           int* __restrict__ top_ws) {
    __shared__ __align__(16) unsigned char smem[SM_BYTES];
    short* xsS = (short*)smem;
    unsigned int* xsW = (unsigned int*)smem;
    short* ysS = (short*)(smem + YS_OFFB);
    float* xnL = (float*)(smem + XN_OFFB);
    float* Dl  = (float*)smem;            // reuses xs region after MFMA

    const int bid = blockIdx.x;
    const int b  = bid >> 8;
    const int t  = bid & 255;
    const int r0 = (t >> 4) * 4;
    const int s0 = (t & 15) * 4;
    const int u0r = min(max(r0 - 15, 0), 32);
    const int u0c = min(max(s0 - 15, 0), 32);
    const int g0c = min(u0c & ~3, 24);    // aligned staged col origin
    const int cofs = u0c - g0c;
    const int tid = threadIdx.x;
    const int l   = tid & 63;
    const int wid = tid >> 6;             // 0..15
    const int lq  = l & 15;
    const int kg  = l >> 4;               // 0..3

    // stage y patches (bf16, e = p*64+c) and xn for the candidate union
    for (int i = tid; i < 16 * 576; i += 1024) {
        int q = i / 576, e = i - q * 576;
        int p = e >> 6, c = e & 63;
        int rq = min(r0 + (q >> 2), 61), sq = min(s0 + (q & 3), 61);
        float v = ye[((b * C_ + c) * HW + rq + p / 3) * HW + sq + p % 3];
        ysS[q * YSTR + e] = (short)f2bf(v);
    }
    for (int i = tid; i < 1089; i += 1024) {
        int cr = i / 33, cc = i - cr * 33;
        int nr = min(u0r + cr, 61), nc = min(u0c + cc, 61);
        xnL[i] = xnp[b * NP + nr * M1 + nc];
    }

    f32x4 acc[5];
    #pragma unroll
    for (int i = 0; i < 5; i++) acc[i] = (f32x4){0.f, 0.f, 0.f, 0.f};

    int prb[5], pcb[5];
    #pragma unroll
    for (int i = 0; i < 5; i++) {
        int ci = (wid * 5 + i) * 16 + lq;  // 0..1279
        int cis = min(ci, 1088);           // clamp phantoms in-bounds
        int cr = cis / 33;
        prb[i] = cr;
        pcb[i] = cis - cr * 33 + cofs;
    }

    for (int ch = 0; ch < 2; ch++) {
        __syncthreads();
        // stage 32-channel half, bf16 channel-last; lanes minor over ch-pair ->
        // write stride across lanes = 1 word (cp) / 840 words (a): 2 lanes/bank
        for (int u = tid; u < 16 * 35; u += 1024) {
            int cp = u & 15, a = u >> 4;
            int c0 = ch * 32 + cp * 2;
            int gr = min(u0r + a, 63);
            const float4* pa = (const float4*)(xe + ((size_t)(b * C_ + c0) * HW + gr) * HW + g0c);
            const float4* pb = (const float4*)(xe + ((size_t)(b * C_ + c0 + 1) * HW + gr) * HW + g0c);
            #pragma unroll
            for (int blk = 0; blk < 10; blk++) {
                float4 va = pa[blk], vb = pb[blk];
                int w0 = (a * UPC + blk * 4) * (CSTR / 2) + cp;  // u32 word index
                xsW[w0                ] = (unsigned)f2bf(va.x) | ((unsigned)f2bf(vb.x) << 16);
                xsW[w0 +     CSTR / 2 ] = (unsigned)f2bf(va.y) | ((unsigned)f2bf(vb.y) << 16);
                xsW[w0 +     CSTR     ] = (unsigned)f2bf(va.z) | ((unsigned)f2bf(vb.z) << 16);
                xsW[w0 + 3 * CSTR / 2 ] = (unsigned)f2bf(va.w) | ((unsigned)f2bf(vb.w) << 16);
            }
        }
        __syncthreads();
        #pragma unroll
        for (int p = 0; p < 9; p++) {
            const int pi = p / 3, pj = p % 3;
            bf16x8 af = *(const bf16x8*)(ysS + lq * YSTR + p * 64 + ch * 32 + kg * 8);
            #pragma unroll
            for (int i = 0; i < 5; i++) {
                const short* bp = xsS + ((prb[i] + pi) * UPC + (pcb[i] + pj)) * CSTR + kg * 8;
                bf16x8 bf = *(const bf16x8*)bp;
                acc[i] = __builtin_amdgcn_mfma_f32_16x16x32_bf16(af, bf, acc[i], 0, 0, 0);
            }
        }
    }

    __syncthreads();
    // epilogue: D = xn - 2*dot into Dl[q][ci] (C layout: col=lane&15, row=(lane>>4)*4+reg)
    #pragma unroll
    for (int i = 0; i < 5; i++) {
        int ci = (wid * 5 + i) * 16 + lq;
        if (ci < 1089) {
            float xnv = xnL[ci];
            #pragma unroll
            for (int j = 0; j < 4; j++) {
                Dl[(kg * 4 + j) * 1089 + ci] = xnv - 2.0f * acc[i][j];
            }
        }
    }
    __syncthreads();

    // wave-level top-16: one query per wave
    {
        int q = wid;
        int rq = r0 + (q >> 2), sq = s0 + (q & 3);
        if (rq <= 61 && sq <= 61) {
            int siq = min(max(rq - 15, 0), 32);
            int sjq = min(max(sq - 15, 0), 32);
            int ro = siq - u0r, co = sjq - u0c;
            float kv[15]; int wv[15];
            #pragma unroll
            for (int kk = 0; kk < 15; kk++) {
                int w = kk * 64 + l;
                if (w < 900) {
                    int wi = w / 30, wj = w - wi * 30;
                    kv[kk] = Dl[q * 1089 + (ro + wi) * 33 + (co + wj)];
                    wv[kk] = w;
                } else { kv[kk] = FLT_MAX; wv[kk] = 1 << 30; }
            }
            int obase = (b * NP + rq * M1 + sq) * NSEL;
            for (int it = 0; it < NSEL; it++) {
                float bk = FLT_MAX; int bw = 1 << 30;
                #pragma unroll
                for (int kk = 0; kk < 15; kk++)
                    if (kv[kk] < bk || (kv[kk] == bk && wv[kk] < bw)) { bk = kv[kk]; bw = wv[kk]; }
                #pragma unroll
                for (int off = 32; off >= 1; off >>= 1) {
                    float ok = __shfl_xor(bk, off);
                    int   ow = __shfl_xor(bw, off);
                    if (ok < bk || (ok == bk && ow < bw)) { bk = ok; bw = ow; }
                }
                #pragma unroll
                for (int kk = 0; kk < 15; kk++)
                    if (wv[kk] == bw) kv[kk] = FLT_MAX;
                if (l == 0) {
                    int wi = bw / 30, wj = bw - wi * 30;
                    top_ws[obase + it] = (siq + wi) * M1 + (sjq + wj);
                }
            }
        }
    }
}

// ---------------- K3: bitwise np-f32 emulation + outputs --------------------
__global__ __launch_bounds__(256) void emu_kernel(const float* __restrict__ xe,
                                                  const float* __restrict__ ye,
                                                  const float* __restrict__ xnp,
                                                  const float* __restrict__ ynp,
                                                  const int* __restrict__ top_ws,
                                                  float* __restrict__ out_idx,
                                                  float* __restrict__ sv_ws,
                                                  float* __restrict__ dsum_ws) {
    __shared__ float ysP[576], ysE[576];
    __shared__ int tab[576];
    __shared__ int topWs[NSEL];
    __shared__ float keyEmu[NSEL];
    __shared__ float selKey[KK];
    __shared__ int   selN[KK];

    const int bid = blockIdx.x;
    const int b = bid / NP, m = bid - b * NP;
    const int r = m / M1, s = m - r * M1;
    const int tid = threadIdx.x;
    const float* xb = xe + (size_t)b * C_ * HW * HW;
    const float* yb = ye + (size_t)b * C_ * HW * HW + r * HW + s;

    for (int t = tid; t < 576; t += 256) {
        int c = t / 9, p = t - c * 9;
        tab[t] = c * (HW * HW) + (p / 3) * HW + (p % 3);
    }
    if (tid < NSEL) topWs[tid] = top_ws[bid * NSEL + tid];
    __syncthreads();

    for (int t = tid; t < 576; t += 256) {
        float v = yb[tab[t]];
        ysE[t] = v;
        int c = t / 9, p = t - c * 9;
        ysP[p * 64 + c] = v;
    }
    __syncthreads();

    {   // einsum E emulation: AVX512 single-vaccum nested-FMA, lane j owns e≡j (mod 16)
        const int cand = tid >> 4, j = tid & 15;
        const int n = topWs[cand];
        const int px = n / M1, py = n - px * M1;
        const float* xp = xb + px * HW + py;
        float acc = 0.f;
        #pragma unroll
        for (int t = 0; t < 36; t++) {
            int e = t * 16 + j;
            acc = fmaf(ysE[e], xp[tab[e]], acc);
        }
        float E = acc;
        E = E + __shfl_xor(E, 8, 16);
        E = E + __shfl_xor(E, 4, 16);
        E = E + __shfl_xor(E, 2, 16);
        E = E + __shfl_xor(E, 1, 16);
        if (j == 0) {
            float t0 = -2.0f * E;
            float k1 = t0 + ynp[b * NP + m];
            float k2 = k1 + xnp[b * NP + n];
            keyEmu[cand] = k2 + 1e-5f;
        }
    }
    __syncthreads();

    if (tid == 0) {
        float d[NSEL]; int w[NSEL];
        for (int i = 0; i < NSEL; i++) { d[i] = keyEmu[i]; w[i] = topWs[i]; }
        for (int a = 1; a < NSEL; a++) {
            float dv = d[a]; int wv2 = w[a]; int p = a - 1;
            while (p >= 0 && (d[p] > dv || (d[p] == dv && w[p] > wv2))) {
                d[p + 1] = d[p]; w[p + 1] = w[p]; p--;
            }
            d[p + 1] = dv; w[p + 1] = wv2;
        }
        for (int i = 0; i < KK; i++) { selKey[i] = d[i]; selN[i] = w[i]; }
    }
    __syncthreads();

    if (tid < KK) {
        out_idx[(b * NP + m) * KK + tid] = (float)selN[tid];
        float s10 = selKey[tid] / 10.0f;
        double sv = exp(-(double)s10);
        sv_ws[(b * KK + tid) * NP + m] = (float)sv;
    }

    for (int pair = tid; pair < KK * C_; pair += 256) {
        int k = pair >> 6, c = pair & 63;
        int n = selN[k];
        int px = n / M1, py = n - px * M1;
        const float* xp = xb + c * (HW * HW) + px * HW + py;
        float a = 0.f;
        #pragma unroll
        for (int pi = 0; pi < 3; pi++) {
            #pragma unroll
            for (int pj = 0; pj < 3; pj++) {
                a += fabsf(ysP[(pi * 3 + pj) * 64 + c] - xp[pi * HW + pj]);
            }
        }
        dsum_ws[((b * KK + k) * C_ + c) * NP + m] = a;
    }
}

// ---------------- overlap-add image kernels ---------------------------------
__device__ __forceinline__ void oa_range(int y, int& r0, int& r1) {
    r0 = (y >= 5) ? ((y - 4) >> 1) : 0;
    r1 = min(M1 - 1, y >> 1);
}

__global__ __launch_bounds__(256) void score_img_kernel(const float* __restrict__ sv_ws,
                                                        float* __restrict__ out) {
    int idx = blockIdx.x * 256 + threadIdx.x;
    if (idx >= OUT_SCORE_SZ) return;
    int x = idx & 127, y = (idx >> 7) & 127;
    int bk = idx >> 14;
    int r0, r1, s0, s1;
    oa_range(y, r0, r1);
    oa_range(x, s0, s1);
    const float* base = sv_ws + bk * NP;
    float acc = 0.f;
    for (int rr = r0; rr <= r1; rr++)
        for (int ss = s0; ss <= s1; ss++)
            acc += base[rr * M1 + ss];
    out[idx] = acc;
}

__global__ __launch_bounds__(256) void diff_img_kernel(const float* __restrict__ dsum_ws,
                                                       float* __restrict__ out) {
    int idx = blockIdx.x * 256 + threadIdx.x;
    if (idx >= OUT_DIFF_SZ) return;
    int x = idx & 127, y = (idx >> 7) & 127;
    int bkc = idx >> 14;
    int r0, r1, s0, s1;
    oa_range(y, r0, r1);
    oa_range(x, s0, s1);
    const float* base = dsum_ws + bkc * NP;
    float acc = 0.f;
    for (int rr = r0; rr <= r1; rr++)
        for (int ss = s0; ss <= s1; ss++)
            acc += base[rr * M1 + ss];
    out[idx] = acc;
}

extern "C" void kernel_launch(void* const* d_in, const int* in_sizes, int n_in,
                              void* d_out, int out_size, void* d_ws, size_t ws_size,
                              hipStream_t stream) {
    const float* xe = (const float*)d_in[0];
    const float* ye = (const float*)d_in[1];
    float* out = (float*)d_out;
    float* ws = (float*)d_ws;

    float* xnp = ws + WS_XNP;
    float* ynp = ws + WS_YNP;
    int*   topw = (int*)(ws + WS_TOP);
    float* sv_ws = ws + WS_SV;
    float* dsum_ws = ws + WS_DSUM;

    norm_np_kernel<<<(2 * B_ * NP * 8 + 255) / 256, 256, 0, stream>>>(xe, ye, xnp, ynp);
    gemm_select_kernel<<<2 * 256, 1024, 0, stream>>>(xe, ye, xnp, topw);
    emu_kernel<<<B_ * NP, 256, 0, stream>>>(xe, ye, xnp, ynp, topw,
                                            out + OUT_IDX_OFF, sv_ws, dsum_ws);
    score_img_kernel<<<OUT_SCORE_SZ / 256, 256, 0, stream>>>(sv_ws, out);
    diff_img_kernel<<<OUT_DIFF_SZ / 256, 256, 0, stream>>>(dsum_ws, out + OUT_DIFF_OFF);
}